// Round 17
// baseline (161.646 us; speedup 1.0000x reference)
//
#include <hip/hip_runtime.h>
#include <hip/hip_cooperative_groups.h>
#include <stdint.h>

namespace cg = cooperative_groups;

namespace {

constexpr int kB = 8;
constexpr int kV = 5023;
constexpr int kF = 9976;
constexpr int kH = 512;
constexpr int kW = 512;
constexpr int kL = 5;
constexpr int kHW = kH * kW;
constexpr int kQ = kHW / 4;   // pixel quads per batch (65536, pow2)
constexpr int kQH = kQ / 2;   // half-range: each thread handles 2 quads
constexpr int kCap = 32;      // max faces per vertex (lambda ~ 6)

// cooperative prep kernel sizing: phase 1 needs kF + kB*kF threads (largest)
constexpr int kCoopThreads = kF + kB * kF;              // 89784
constexpr int kCoopBlocks = (kCoopThreads + 255) / 256; // 351

typedef float nfloat4 __attribute__((ext_vector_type(4)));

__device__ __forceinline__ float h2f(uint32_t u) {
  _Float16 h;
  uint16_t s = (uint16_t)u;
  __builtin_memcpy(&h, &s, 2);
  return (float)h;
}
__device__ __forceinline__ uint32_t f2h(float f) {
  _Float16 h = (_Float16)f;
  uint16_t s;
  __builtin_memcpy(&s, &h, 2);
  return (uint32_t)s;
}

__device__ __forceinline__ void cross3(float ax, float ay, float az,
                                       float bx, float by, float bz,
                                       float& cx, float& cy, float& cz) {
  cx = ay * bz - az * by;
  cy = az * bx - ax * bz;
  cz = ax * by - ay * bx;
}

// ---- Fused prep: init -> adjacency+facenormals -> gather_normalize ->
// faceattr, one cooperative launch with grid.sync() between phases.
// Replaces 4 serial dispatches (~9us incl. launch gaps) with one (~3-4us).
__global__ void fused_prep_kernel(const float* __restrict__ verts,
                                  const float* __restrict__ tverts,
                                  const int* __restrict__ faces,
                                  const float* __restrict__ lights,
                                  int* __restrict__ cnt,
                                  int* __restrict__ adj,
                                  float4* __restrict__ fn,
                                  uint4* __restrict__ vrec,
                                  uint4* __restrict__ fattr,
                                  float4* __restrict__ ldir4) {
  cg::grid_group grid = cg::this_grid();
  const int idx = blockIdx.x * blockDim.x + threadIdx.x;
  const int nthr = gridDim.x * blockDim.x;

  // ---- phase 0: zero adjacency counters; normalize lights ----
  for (int i = idx; i < kV; i += nthr) cnt[i] = 0;
  if (idx < kB * kL) {
    float dx = lights[idx * 6 + 0];
    float dy = lights[idx * 6 + 1];
    float dz = lights[idx * 6 + 2];
    float inv = 1.0f / fmaxf(sqrtf(dx * dx + dy * dy + dz * dz), 1e-12f);
    ldir4[idx * 2 + 0] = make_float4(dx * inv, dy * inv, dz * inv, 0.0f);
    ldir4[idx * 2 + 1] =
        make_float4(lights[idx * 6 + 3], lights[idx * 6 + 4], lights[idx * 6 + 5], 0.0f);
  }
  grid.sync();

  // ---- phase 1: adjacency (idx<kF) + face normals (idx in [kF, kF+kB*kF)) ----
  if (idx < kF) {
    int f = idx;
#pragma unroll
    for (int c = 0; c < 3; ++c) {
      int v = faces[f * 3 + c];
      int slot = atomicAdd(&cnt[v], 1);
      if (slot < kCap) adj[v * kCap + slot] = f;
    }
  } else if (idx < kF + kB * kF) {
    int j = idx - kF;
    int b = j / kF;
    int f = j - b * kF;
    int i0 = faces[f * 3 + 0];
    int i1 = faces[f * 3 + 1];
    int i2 = faces[f * 3 + 2];
    float nx, ny, nz, tx, ty, tz;
    {
      const float* vb = verts + (size_t)b * kV * 3;
      float v0x = vb[i0 * 3 + 0], v0y = vb[i0 * 3 + 1], v0z = vb[i0 * 3 + 2];
      float v1x = vb[i1 * 3 + 0], v1y = vb[i1 * 3 + 1], v1z = vb[i1 * 3 + 2];
      float v2x = vb[i2 * 3 + 0], v2y = vb[i2 * 3 + 1], v2z = vb[i2 * 3 + 2];
      cross3(v1x - v0x, v1y - v0y, v1z - v0z, v2x - v0x, v2y - v0y, v2z - v0z,
             nx, ny, nz);
    }
    {
      const float* vb = tverts + (size_t)b * kV * 3;
      // fp-faithful to reference: add 10 to z BEFORE differencing
      float v0x = vb[i0 * 3 + 0], v0y = vb[i0 * 3 + 1], v0z = vb[i0 * 3 + 2] + 10.0f;
      float v1x = vb[i1 * 3 + 0], v1y = vb[i1 * 3 + 1], v1z = vb[i1 * 3 + 2] + 10.0f;
      float v2x = vb[i2 * 3 + 0], v2y = vb[i2 * 3 + 1], v2z = vb[i2 * 3 + 2] + 10.0f;
      cross3(v1x - v0x, v1y - v0y, v1z - v0z, v2x - v0x, v2y - v0y, v2z - v0z,
             tx, ty, tz);
    }
    fn[(size_t)j * 2 + 0] = make_float4(nx, ny, nz, tx);
    fn[(size_t)j * 2 + 1] = make_float4(ty, tz, 0.0f, 0.0f);
  }
  grid.sync();

  // ---- phase 2: per (b,v) gather-sum + normalize -> 16B vrec ----
  if (idx < kB * kV) {
    int b = idx / kV;
    int v = idx - b * kV;
    int e = min(cnt[v], kCap);
    float nx = 0.f, ny = 0.f, nz = 0.f, tx = 0.f, ty = 0.f, tzv = 0.f;
    const int* av = adj + v * kCap;
    for (int j = 0; j < e; ++j) {
      int f = av[j];
      size_t k = ((size_t)b * kF + f) * 2;
      float4 a = fn[k];
      float4 c = fn[k + 1];
      nx += a.x;
      ny += a.y;
      nz += a.z;
      tx += a.w;
      ty += c.x;
      tzv += c.y;
    }
    float inv = 1.0f / fmaxf(sqrtf(nx * nx + ny * ny + nz * nz), 1e-6f);
    float invt = 1.0f / fmaxf(sqrtf(tx * tx + ty * ty + tzv * tzv), 1e-6f);
    uint4 r;
    r.x = f2h(nx * inv) | (f2h(ny * inv) << 16);
    r.y = f2h(nz * inv);
    r.z = __float_as_uint(tzv * invt);
    r.w = 0;
    vrec[idx] = r;
  }
  grid.sync();

  // ---- phase 3: per (b,f) pack 32B face record ----
  if (idx < kB * kF) {
    int b = idx / kF;
    int f = idx - b * kF;
    int i0 = faces[f * 3 + 0];
    int i1 = faces[f * 3 + 1];
    int i2 = faces[f * 3 + 2];
    const uint4* vb = vrec + (size_t)b * kV;
    uint4 r0 = vb[i0];
    uint4 r1 = vb[i1];
    uint4 r2 = vb[i2];
    uint4 w0, w1;
    w0.x = r0.x;
    w0.y = (r0.y & 0xffffu) | (r1.x << 16);
    w0.z = (r1.x >> 16) | ((r1.y & 0xffffu) << 16);
    w0.w = r2.x;
    w1.x = r2.y & 0xffffu;
    w1.y = r0.z;
    w1.z = r1.z;
    w1.w = r2.z;
    fattr[(size_t)idx * 2 + 0] = w0;
    fattr[(size_t)idx * 2 + 1] = w1;
  }
}

// Shade one quad given its loaded inputs (compile-time-unrolled helper).
__device__ __forceinline__ void shade_quad(
    const int4& f4, const float4& w0, const float4& w1, const float4& w2,
    const uint4* A, const uint4* T,
    const float4& im0, const float4& im1, const float4& im2,
    const float4* lb4, float o[3][4]) {
  int fi[4] = {f4.x, f4.y, f4.z, f4.w};
  float bw[4][3] = {{w0.x, w0.y, w0.z},
                    {w0.w, w1.x, w1.y},
                    {w1.z, w1.w, w2.x},
                    {w2.y, w2.z, w2.w}};
  float im[3][4] = {{im0.x, im0.y, im0.z, im0.w},
                    {im1.x, im1.y, im1.z, im1.w},
                    {im2.x, im2.y, im2.z, im2.w}};
#pragma unroll
  for (int k = 0; k < 4; ++k) {
    float b0 = bw[k][0], b1 = bw[k][1], b2 = bw[k][2];
    float inv = 1.0f / (b0 + b1 + b2);
    b0 *= inv;
    b1 *= inv;
    b2 *= inv;
    float n0x = h2f(A[k].x), n0y = h2f(A[k].x >> 16);
    float n0z = h2f(A[k].y), n1x = h2f(A[k].y >> 16);
    float n1y = h2f(A[k].z), n1z = h2f(A[k].z >> 16);
    float n2x = h2f(A[k].w), n2y = h2f(A[k].w >> 16);
    float n2z = h2f(T[k].x);
    float tz0 = __uint_as_float(T[k].y);
    float tz1 = __uint_as_float(T[k].z);
    float tz2 = __uint_as_float(T[k].w);

    float tzi = b0 * tz0 + b1 * tz1 + b2 * tz2;
    bool alpha = (fi[k] < kF) && (tzi < 0.15f);
    float nx = b0 * n0x + b1 * n1x + b2 * n2x;
    float ny = b0 * n0y + b1 * n1y + b2 * n2y;
    float nz = b0 * n0z + b1 * n1z + b2 * n2z;
    float s0 = 0.f, s1 = 0.f, s2 = 0.f;
#pragma unroll
    for (int l = 0; l < kL; ++l) {
      float4 d4 = lb4[l * 2 + 0];
      float4 c4 = lb4[l * 2 + 1];
      float d = nx * d4.x + ny * d4.y + nz * d4.z;
      d = fminf(fmaxf(d, 0.0f), 1.0f);
      s0 += d * c4.x;
      s1 += d * c4.y;
      s2 += d * c4.z;
    }
    const float kk = (180.0f / 255.0f) / (float)kL;
    o[0][k] = alpha ? kk * s0 : im[0][k];
    o[1][k] = alpha ? kk * s1 : im[1][k];
    o[2][k] = alpha ? kk * s2 : im[2][k];
  }
}

// 8 pixels per thread: TWO quads, all loads for BOTH issued before any
// compute (round-16 best config: plain loads + NT stores, XCD-affine).
__global__ void __launch_bounds__(256) pixel8_kernel(
    const int4* __restrict__ p2f4,
    const float4* __restrict__ bary4,
    const uint4* __restrict__ fattr,
    const float4* __restrict__ ldir4,
    const float4* __restrict__ img4,
    float4* __restrict__ out4) {
  int b = blockIdx.x & 7;
  int q0 = (blockIdx.x >> 3) * blockDim.x + threadIdx.x;  // [0, kQH)
  int q1 = q0 + kQH;
  size_t gA = (size_t)b * kQ + q0;
  size_t gB = (size_t)b * kQ + q1;

  // ---- issue ALL loads for both quads ----
  int4 fA = p2f4[gA];
  int4 fB = p2f4[gB];
  float4 wA0 = bary4[gA * 3 + 0];
  float4 wA1 = bary4[gA * 3 + 1];
  float4 wA2 = bary4[gA * 3 + 2];
  float4 wB0 = bary4[gB * 3 + 0];
  float4 wB1 = bary4[gB * 3 + 1];
  float4 wB2 = bary4[gB * 3 + 2];

  size_t ibA = (size_t)b * 3 * kQ + q0;
  size_t ibB = (size_t)b * 3 * kQ + q1;
  float4 iA0 = img4[ibA + 0 * (size_t)kQ];
  float4 iA1 = img4[ibA + 1 * (size_t)kQ];
  float4 iA2 = img4[ibA + 2 * (size_t)kQ];
  float4 iB0 = img4[ibB + 0 * (size_t)kQ];
  float4 iB1 = img4[ibB + 1 * (size_t)kQ];
  float4 iB2 = img4[ibB + 2 * (size_t)kQ];

  uint4 AA[4], TA[4], AB[4], TB[4];
  {
    int fiA[4] = {fA.x, fA.y, fA.z, fA.w};
    int fiB[4] = {fB.x, fB.y, fB.z, fB.w};
#pragma unroll
    for (int k = 0; k < 4; ++k) {
      int f = (fiA[k] < kF) ? fiA[k] : (kF - 1);
      size_t base = ((size_t)b * kF + f) * 2;
      AA[k] = fattr[base + 0];
      TA[k] = fattr[base + 1];
    }
#pragma unroll
    for (int k = 0; k < 4; ++k) {
      int f = (fiB[k] < kF) ? fiB[k] : (kF - 1);
      size_t base = ((size_t)b * kF + f) * 2;
      AB[k] = fattr[base + 0];
      TB[k] = fattr[base + 1];
    }
  }

  // Light data: wave-uniform -> scalar loads (SGPRs, not VGPRs).
  int bu = __builtin_amdgcn_readfirstlane(b);
  const float4* lb4 = ldir4 + (size_t)bu * kL * 2;

  // ---- shade + store quad A, then quad B ----
  float oA[3][4];
  shade_quad(fA, wA0, wA1, wA2, AA, TA, iA0, iA1, iA2, lb4, oA);
#pragma unroll
  for (int c = 0; c < 3; ++c) {
    nfloat4 v = {oA[c][0], oA[c][1], oA[c][2], oA[c][3]};
    __builtin_nontemporal_store(v, (nfloat4*)&out4[ibA + c * (size_t)kQ]);
  }

  float oB[3][4];
  shade_quad(fB, wB0, wB1, wB2, AB, TB, iB0, iB1, iB2, lb4, oB);
#pragma unroll
  for (int c = 0; c < 3; ++c) {
    nfloat4 v = {oB[c][0], oB[c][1], oB[c][2], oB[c][3]};
    __builtin_nontemporal_store(v, (nfloat4*)&out4[ibB + c * (size_t)kQ]);
  }
}

}  // namespace

extern "C" void kernel_launch(void* const* d_in, const int* in_sizes, int n_in,
                              void* d_out, int out_size, void* d_ws, size_t ws_size,
                              hipStream_t stream) {
  const float* vertices = (const float*)d_in[0];
  const float* tvertices = (const float*)d_in[1];
  const float* lights = (const float*)d_in[2];
  const float* images = (const float*)d_in[3];
  const float* bary = (const float*)d_in[4];
  const int* faces = (const int*)d_in[5];
  const int* p2f = (const int*)d_in[6];
  float* out = (float*)d_out;

  // workspace layout (16B-aligned chunks)
  char* ws = (char*)d_ws;
  int* cnt = (int*)ws;                                   // kV ints
  ws += ((size_t)kV * sizeof(int) + 15) & ~15ull;
  int* adj = (int*)ws;                                   // kV*kCap ints
  ws += ((size_t)kV * kCap * sizeof(int) + 15) & ~15ull;
  float4* fn = (float4*)ws;                              // kB*kF*2 float4
  ws += (size_t)kB * kF * 2 * sizeof(float4);
  uint4* vrec = (uint4*)ws;                              // kB*kV uint4
  ws += (size_t)kB * kV * sizeof(uint4);
  float4* ldir4 = (float4*)ws;                           // kB*kL*2 float4
  ws += (size_t)kB * kL * 2 * sizeof(float4);
  uint4* fattr = (uint4*)ws;                             // kB*kF*2 uint4

  {
    // one cooperative launch replaces init/prep/gather_normalize/faceattr
    void* args[] = {(void*)&vertices, (void*)&tvertices, (void*)&faces,
                    (void*)&lights,   (void*)&cnt,       (void*)&adj,
                    (void*)&fn,       (void*)&vrec,      (void*)&fattr,
                    (void*)&ldir4};
    hipLaunchCooperativeKernel((const void*)fused_prep_kernel,
                               dim3(kCoopBlocks), dim3(256), args, 0, stream);
  }
  {
    // 1024 blocks, 2 quads (8 px) per thread, all loads issued up front.
    pixel8_kernel<<<(kQH / 256) * kB, 256, 0, stream>>>(
        (const int4*)p2f, (const float4*)bary, fattr, ldir4, (const float4*)images,
        (float4*)out);
  }
}

// Round 18
// 46.861 us; speedup vs baseline: 3.4495x; 3.4495x over previous
//
#include <hip/hip_runtime.h>
#include <stdint.h>

namespace {

constexpr int kB = 8;
constexpr int kV = 5023;
constexpr int kF = 9976;
constexpr int kH = 512;
constexpr int kW = 512;
constexpr int kL = 5;
constexpr int kHW = kH * kW;
constexpr int kQ = kHW / 4;   // pixel quads per batch (65536, pow2)
constexpr int kQH = kQ / 2;   // half-range: each thread handles 2 quads
constexpr int kCap = 32;      // max faces per vertex (lambda ~ 6)

typedef float nfloat4 __attribute__((ext_vector_type(4)));

__device__ __forceinline__ float h2f(uint32_t u) {
  _Float16 h;
  uint16_t s = (uint16_t)u;
  __builtin_memcpy(&h, &s, 2);
  return (float)h;
}
__device__ __forceinline__ uint32_t f2h(float f) {
  _Float16 h = (_Float16)f;
  uint16_t s;
  __builtin_memcpy(&s, &h, 2);
  return (uint32_t)s;
}

__device__ __forceinline__ void cross3(float ax, float ay, float az,
                                       float bx, float by, float bz,
                                       float& cx, float& cy, float& cz) {
  cx = ay * bz - az * by;
  cy = az * bx - ax * bz;
  cz = ax * by - ay * bx;
}

// Zero adjacency counters + pre-normalize lights into packed float4 pairs.
__global__ void init_kernel(int* __restrict__ cnt,
                            const float* __restrict__ lights,
                            float4* __restrict__ ldir4) {
  int idx = blockIdx.x * blockDim.x + threadIdx.x;
  for (int i = idx; i < kV; i += gridDim.x * blockDim.x) cnt[i] = 0;
  if (idx < kB * kL) {
    float dx = lights[idx * 6 + 0];
    float dy = lights[idx * 6 + 1];
    float dz = lights[idx * 6 + 2];
    float inv = 1.0f / fmaxf(sqrtf(dx * dx + dy * dy + dz * dz), 1e-12f);
    ldir4[idx * 2 + 0] = make_float4(dx * inv, dy * inv, dz * inv, 0.0f);
    ldir4[idx * 2 + 1] =
        make_float4(lights[idx * 6 + 3], lights[idx * 6 + 4], lights[idx * 6 + 5], 0.0f);
  }
}

// Fused: threads [0,kF) build vertex->face adjacency (int atomics);
// threads [kF, kF+kB*kF) compute per-(b,f) face normals for both meshes.
__global__ void prep_kernel(const float* __restrict__ verts,
                            const float* __restrict__ tverts,
                            const int* __restrict__ faces,
                            int* __restrict__ cnt,
                            int* __restrict__ adj,
                            float4* __restrict__ fn) {
  int idx = blockIdx.x * blockDim.x + threadIdx.x;
  if (idx < kF) {
    int f = idx;
#pragma unroll
    for (int c = 0; c < 3; ++c) {
      int v = faces[f * 3 + c];
      int slot = atomicAdd(&cnt[v], 1);
      if (slot < kCap) adj[v * kCap + slot] = f;
    }
    return;
  }
  idx -= kF;
  if (idx >= kB * kF) return;
  int b = idx / kF;
  int f = idx - b * kF;
  int i0 = faces[f * 3 + 0];
  int i1 = faces[f * 3 + 1];
  int i2 = faces[f * 3 + 2];

  float nx, ny, nz, tx, ty, tz;
  {
    const float* vb = verts + (size_t)b * kV * 3;
    float v0x = vb[i0 * 3 + 0], v0y = vb[i0 * 3 + 1], v0z = vb[i0 * 3 + 2];
    float v1x = vb[i1 * 3 + 0], v1y = vb[i1 * 3 + 1], v1z = vb[i1 * 3 + 2];
    float v2x = vb[i2 * 3 + 0], v2y = vb[i2 * 3 + 1], v2z = vb[i2 * 3 + 2];
    cross3(v1x - v0x, v1y - v0y, v1z - v0z, v2x - v0x, v2y - v0y, v2z - v0z,
           nx, ny, nz);
  }
  {
    const float* vb = tverts + (size_t)b * kV * 3;
    // fp-faithful to reference: add 10 to z BEFORE differencing
    float v0x = vb[i0 * 3 + 0], v0y = vb[i0 * 3 + 1], v0z = vb[i0 * 3 + 2] + 10.0f;
    float v1x = vb[i1 * 3 + 0], v1y = vb[i1 * 3 + 1], v1z = vb[i1 * 3 + 2] + 10.0f;
    float v2x = vb[i2 * 3 + 0], v2y = vb[i2 * 3 + 1], v2z = vb[i2 * 3 + 2] + 10.0f;
    cross3(v1x - v0x, v1y - v0y, v1z - v0z, v2x - v0x, v2y - v0y, v2z - v0z,
           tx, ty, tz);
  }
  fn[(size_t)idx * 2 + 0] = make_float4(nx, ny, nz, tx);
  fn[(size_t)idx * 2 + 1] = make_float4(ty, tz, 0.0f, 0.0f);
}

// Per (b,v): gather-sum adjacent face normals, normalize, write packed
// 16B vertex record {nx|ny fp16, nz fp16, tz fp32, 0}.
__global__ void gather_normalize_kernel(const int* __restrict__ cnt,
                                        const int* __restrict__ adj,
                                        const float4* __restrict__ fn,
                                        uint4* __restrict__ vrec) {
  int idx = blockIdx.x * blockDim.x + threadIdx.x;
  if (idx >= kB * kV) return;
  int b = idx / kV;
  int v = idx - b * kV;
  int e = min(cnt[v], kCap);
  float nx = 0.f, ny = 0.f, nz = 0.f, tx = 0.f, ty = 0.f, tzv = 0.f;
  const int* av = adj + v * kCap;
  for (int j = 0; j < e; ++j) {
    int f = av[j];
    size_t k = ((size_t)b * kF + f) * 2;
    float4 a = fn[k];
    float4 c = fn[k + 1];
    nx += a.x;
    ny += a.y;
    nz += a.z;
    tx += a.w;
    ty += c.x;
    tzv += c.y;
  }
  float inv = 1.0f / fmaxf(sqrtf(nx * nx + ny * ny + nz * nz), 1e-6f);
  float invt = 1.0f / fmaxf(sqrtf(tx * tx + ty * ty + tzv * tzv), 1e-6f);
  uint4 r;
  r.x = f2h(nx * inv) | (f2h(ny * inv) << 16);
  r.y = f2h(nz * inv);
  r.z = __float_as_uint(tzv * invt);
  r.w = 0;
  vrec[idx] = r;
}

// Per (b,f): pull 3 packed vertex records and repack into the 32B face
// record. XCD-affine.
__global__ void faceattr_kernel(const int* __restrict__ faces,
                                const uint4* __restrict__ vrec,
                                uint4* __restrict__ fattr) {
  int b = blockIdx.x % kB;
  int f = (blockIdx.x / kB) * blockDim.x + threadIdx.x;
  if (f >= kF) return;
  int idx = b * kF + f;
  int i0 = faces[f * 3 + 0];
  int i1 = faces[f * 3 + 1];
  int i2 = faces[f * 3 + 2];
  const uint4* vb = vrec + (size_t)b * kV;
  uint4 r0 = vb[i0];
  uint4 r1 = vb[i1];
  uint4 r2 = vb[i2];
  uint4 w0, w1;
  w0.x = r0.x;
  w0.y = (r0.y & 0xffffu) | (r1.x << 16);
  w0.z = (r1.x >> 16) | ((r1.y & 0xffffu) << 16);
  w0.w = r2.x;
  w1.x = r2.y & 0xffffu;
  w1.y = r0.z;
  w1.z = r1.z;
  w1.w = r2.z;
  fattr[(size_t)idx * 2 + 0] = w0;
  fattr[(size_t)idx * 2 + 1] = w1;
}

// Shade one quad given its loaded inputs (compile-time-unrolled helper).
__device__ __forceinline__ void shade_quad(
    const int4& f4, const float4& w0, const float4& w1, const float4& w2,
    const uint4* A, const uint4* T,
    const float4& im0, const float4& im1, const float4& im2,
    const float4* lb4, float o[3][4]) {
  int fi[4] = {f4.x, f4.y, f4.z, f4.w};
  float bw[4][3] = {{w0.x, w0.y, w0.z},
                    {w0.w, w1.x, w1.y},
                    {w1.z, w1.w, w2.x},
                    {w2.y, w2.z, w2.w}};
  float im[3][4] = {{im0.x, im0.y, im0.z, im0.w},
                    {im1.x, im1.y, im1.z, im1.w},
                    {im2.x, im2.y, im2.z, im2.w}};
#pragma unroll
  for (int k = 0; k < 4; ++k) {
    float b0 = bw[k][0], b1 = bw[k][1], b2 = bw[k][2];
    float inv = 1.0f / (b0 + b1 + b2);
    b0 *= inv;
    b1 *= inv;
    b2 *= inv;
    float n0x = h2f(A[k].x), n0y = h2f(A[k].x >> 16);
    float n0z = h2f(A[k].y), n1x = h2f(A[k].y >> 16);
    float n1y = h2f(A[k].z), n1z = h2f(A[k].z >> 16);
    float n2x = h2f(A[k].w), n2y = h2f(A[k].w >> 16);
    float n2z = h2f(T[k].x);
    float tz0 = __uint_as_float(T[k].y);
    float tz1 = __uint_as_float(T[k].z);
    float tz2 = __uint_as_float(T[k].w);

    float tzi = b0 * tz0 + b1 * tz1 + b2 * tz2;
    bool alpha = (fi[k] < kF) && (tzi < 0.15f);
    float nx = b0 * n0x + b1 * n1x + b2 * n2x;
    float ny = b0 * n0y + b1 * n1y + b2 * n2y;
    float nz = b0 * n0z + b1 * n1z + b2 * n2z;
    float s0 = 0.f, s1 = 0.f, s2 = 0.f;
#pragma unroll
    for (int l = 0; l < kL; ++l) {
      float4 d4 = lb4[l * 2 + 0];
      float4 c4 = lb4[l * 2 + 1];
      float d = nx * d4.x + ny * d4.y + nz * d4.z;
      d = fminf(fmaxf(d, 0.0f), 1.0f);
      s0 += d * c4.x;
      s1 += d * c4.y;
      s2 += d * c4.z;
    }
    const float kk = (180.0f / 255.0f) / (float)kL;
    o[0][k] = alpha ? kk * s0 : im[0][k];
    o[1][k] = alpha ? kk * s1 : im[1][k];
    o[2][k] = alpha ? kk * s2 : im[2][k];
  }
}

// 8 pixels per thread: TWO quads, all loads for BOTH issued before any
// compute (clean ILP-2; plain loads + NT stores; XCD-affine). Round-16 best.
__global__ void __launch_bounds__(256) pixel8_kernel(
    const int4* __restrict__ p2f4,
    const float4* __restrict__ bary4,
    const uint4* __restrict__ fattr,
    const float4* __restrict__ ldir4,
    const float4* __restrict__ img4,
    float4* __restrict__ out4) {
  int b = blockIdx.x & 7;
  int q0 = (blockIdx.x >> 3) * blockDim.x + threadIdx.x;  // [0, kQH)
  int q1 = q0 + kQH;
  size_t gA = (size_t)b * kQ + q0;
  size_t gB = (size_t)b * kQ + q1;

  // ---- issue ALL loads for both quads ----
  int4 fA = p2f4[gA];
  int4 fB = p2f4[gB];
  float4 wA0 = bary4[gA * 3 + 0];
  float4 wA1 = bary4[gA * 3 + 1];
  float4 wA2 = bary4[gA * 3 + 2];
  float4 wB0 = bary4[gB * 3 + 0];
  float4 wB1 = bary4[gB * 3 + 1];
  float4 wB2 = bary4[gB * 3 + 2];

  size_t ibA = (size_t)b * 3 * kQ + q0;
  size_t ibB = (size_t)b * 3 * kQ + q1;
  float4 iA0 = img4[ibA + 0 * (size_t)kQ];
  float4 iA1 = img4[ibA + 1 * (size_t)kQ];
  float4 iA2 = img4[ibA + 2 * (size_t)kQ];
  float4 iB0 = img4[ibB + 0 * (size_t)kQ];
  float4 iB1 = img4[ibB + 1 * (size_t)kQ];
  float4 iB2 = img4[ibB + 2 * (size_t)kQ];

  uint4 AA[4], TA[4], AB[4], TB[4];
  {
    int fiA[4] = {fA.x, fA.y, fA.z, fA.w};
    int fiB[4] = {fB.x, fB.y, fB.z, fB.w};
#pragma unroll
    for (int k = 0; k < 4; ++k) {
      int f = (fiA[k] < kF) ? fiA[k] : (kF - 1);
      size_t base = ((size_t)b * kF + f) * 2;
      AA[k] = fattr[base + 0];
      TA[k] = fattr[base + 1];
    }
#pragma unroll
    for (int k = 0; k < 4; ++k) {
      int f = (fiB[k] < kF) ? fiB[k] : (kF - 1);
      size_t base = ((size_t)b * kF + f) * 2;
      AB[k] = fattr[base + 0];
      TB[k] = fattr[base + 1];
    }
  }

  // Light data: wave-uniform -> scalar loads (SGPRs, not VGPRs).
  int bu = __builtin_amdgcn_readfirstlane(b);
  const float4* lb4 = ldir4 + (size_t)bu * kL * 2;

  // ---- shade + store quad A, then quad B ----
  float oA[3][4];
  shade_quad(fA, wA0, wA1, wA2, AA, TA, iA0, iA1, iA2, lb4, oA);
#pragma unroll
  for (int c = 0; c < 3; ++c) {
    nfloat4 v = {oA[c][0], oA[c][1], oA[c][2], oA[c][3]};
    __builtin_nontemporal_store(v, (nfloat4*)&out4[ibA + c * (size_t)kQ]);
  }

  float oB[3][4];
  shade_quad(fB, wB0, wB1, wB2, AB, TB, iB0, iB1, iB2, lb4, oB);
#pragma unroll
  for (int c = 0; c < 3; ++c) {
    nfloat4 v = {oB[c][0], oB[c][1], oB[c][2], oB[c][3]};
    __builtin_nontemporal_store(v, (nfloat4*)&out4[ibB + c * (size_t)kQ]);
  }
}

}  // namespace

extern "C" void kernel_launch(void* const* d_in, const int* in_sizes, int n_in,
                              void* d_out, int out_size, void* d_ws, size_t ws_size,
                              hipStream_t stream) {
  const float* vertices = (const float*)d_in[0];
  const float* tvertices = (const float*)d_in[1];
  const float* lights = (const float*)d_in[2];
  const float* images = (const float*)d_in[3];
  const float* bary = (const float*)d_in[4];
  const int* faces = (const int*)d_in[5];
  const int* p2f = (const int*)d_in[6];
  float* out = (float*)d_out;

  // workspace layout (16B-aligned chunks)
  char* ws = (char*)d_ws;
  int* cnt = (int*)ws;                                   // kV ints
  ws += ((size_t)kV * sizeof(int) + 15) & ~15ull;
  int* adj = (int*)ws;                                   // kV*kCap ints
  ws += ((size_t)kV * kCap * sizeof(int) + 15) & ~15ull;
  float4* fn = (float4*)ws;                              // kB*kF*2 float4
  ws += (size_t)kB * kF * 2 * sizeof(float4);
  uint4* vrec = (uint4*)ws;                              // kB*kV uint4
  ws += (size_t)kB * kV * sizeof(uint4);
  float4* ldir4 = (float4*)ws;                           // kB*kL*2 float4
  ws += (size_t)kB * kL * 2 * sizeof(float4);
  uint4* fattr = (uint4*)ws;                             // kB*kF*2 uint4

  {
    init_kernel<<<20, 256, 0, stream>>>(cnt, lights, ldir4);
  }
  {
    int n = kF + kB * kF;
    prep_kernel<<<(n + 255) / 256, 256, 0, stream>>>(vertices, tvertices, faces, cnt,
                                                     adj, fn);
  }
  {
    int n = kB * kV;
    gather_normalize_kernel<<<(n + 255) / 256, 256, 0, stream>>>(cnt, adj, fn, vrec);
  }
  {
    int chunks = (kF + 255) / 256;
    faceattr_kernel<<<chunks * kB, 256, 0, stream>>>(faces, vrec, fattr);
  }
  {
    // 1024 blocks, 2 quads (8 px) per thread, all loads issued up front.
    pixel8_kernel<<<(kQH / 256) * kB, 256, 0, stream>>>(
        (const int4*)p2f, (const float4*)bary, fattr, ldir4, (const float4*)images,
        (float4*)out);
  }
}